// Round 6
// baseline (416.876 us; speedup 1.0000x reference)
//
#include <hip/hip_runtime.h>
#include <float.h>
#include <math.h>

#define NROWS 65536
#define DIM 256
#define NCODES 2048

typedef _Float16 f16x8 __attribute__((ext_vector_type(8)));
typedef float    f32x4 __attribute__((ext_vector_type(4)));

__device__ __forceinline__ void ld16(const void* g, void* l) {
    __builtin_amdgcn_global_load_lds(
        (__attribute__((address_space(1))) void*)g,
        (__attribute__((address_space(3))) void*)l, 16, 0, 0);
}

// -------- split fp32 -> (hi, lo) fp16, 8 elems/thread; z and cb in one launch --------
__global__ void split_all_kernel(const float* __restrict__ z, _Float16* __restrict__ zh,
                                 _Float16* __restrict__ zl, const float* __restrict__ cb,
                                 _Float16* __restrict__ wh, _Float16* __restrict__ wl) {
    const float* x; _Float16 *hi, *lo; int i;
    if (blockIdx.x < 8192) {
        i = (blockIdx.x * 256 + threadIdx.x) * 8; x = z; hi = zh; lo = zl;
    } else {
        i = ((blockIdx.x - 8192) * 256 + threadIdx.x) * 8; x = cb; hi = wh; lo = wl;
    }
    float4 a = *(const float4*)(x + i);
    float4 b = *(const float4*)(x + i + 4);
    float v[8] = {a.x, a.y, a.z, a.w, b.x, b.y, b.z, b.w};
    _Float16 h[8], l[8];
    #pragma unroll
    for (int k = 0; k < 8; k++) {
        h[k] = (_Float16)v[k];
        l[k] = (_Float16)(v[k] - (float)h[k]);   // v - (float)h is exact in fp32
    }
    *(f16x8*)(hi + i) = *(const f16x8*)h;
    *(f16x8*)(lo + i) = *(const f16x8*)l;
}

// -------- codebook squared norms (fp32 exact): one wave per code --------
__global__ void cbsq_kernel(const float* __restrict__ cb, float* __restrict__ cbsq) {
    int wid  = (blockIdx.x * blockDim.x + threadIdx.x) >> 6;
    int lane = threadIdx.x & 63;
    const float4* c4 = (const float4*)cb;
    float4 v = c4[wid * 64 + lane];
    float s = v.x * v.x + v.y * v.y + v.z * v.z + v.w * v.w;
    #pragma unroll
    for (int m = 32; m >= 1; m >>= 1) s += __shfl_xor(s, m, 64);
    if (lane == 0) cbsq[wid] = s;
}

// -------- MFMA argmin: 512 blocks x 256 thr (4 waves, 2x2 wave grid) --------
// Block tile: 128 rows x 2048 codes (16 chunks of 128 codes), K-steps of 32.
// LDS 72 KB -> TWO blocks co-resident per CU = two independent barrier
// domains (m114 overlap: one block's MFMA covers the other's stage/wait).
// Per-wave layout, swizzle, staging shape, MFMA order identical to the
// verified 198.7us kernel (wave tile 64x64 instead of 64x128).
// dot = zh*wh + zh*wl + zl*wh  (fp16 split; zl*wl term ~2^-24, dropped)
__global__ __launch_bounds__(256, 2)
void argmin_kernel(const _Float16* __restrict__ zh, const _Float16* __restrict__ zl,
                   const _Float16* __restrict__ wh, const _Float16* __restrict__ wl,
                   const float* __restrict__ cbsq, float* __restrict__ idx_out) {
    __shared__ _Float16 Ah[2][128 * 32];   // 2 x 8 KB
    __shared__ _Float16 Al[2][128 * 32];   // 2 x 8 KB
    __shared__ _Float16 Bh[2][128 * 32];   // 2 x 8 KB
    __shared__ _Float16 Bl[2][128 * 32];   // 2 x 8 KB
    __shared__ float cbsq_lds[NCODES];     // 8 KB  -> total 72 KB

    const int t    = threadIdx.x;
    const int wave = t >> 6;
    const int lane = t & 63;
    const int quad = lane >> 4;
    const int l15  = lane & 15;
    const int wr0  = (wave >> 1) * 64;    // wave row offset within block tile
    const int wc0  = (wave & 1) * 64;     // wave code offset within chunk
    const int row0 = blockIdx.x * 128;

    // swizzled read offset (granule of 8 halves): pos = quad ^ ((row>>1)&3)
    const int p8 = (quad ^ ((l15 >> 1) & 3)) * 8;

    // stage cbsq into LDS: 2 issues x 256 thr x 16 B = 8 KB (linear dest per wave)
    #pragma unroll
    for (int it = 0; it < 2; it++) {
        int s = it * 256 + t;
        ld16(cbsq + s * 4, &cbsq_lds[s * 4]);
    }

    // prologue: stage step 0 (cc=0, kc=0) into buffer 0 (8 ld16/thread)
    #pragma unroll
    for (int it = 0; it < 2; it++) {
        int s = it * 256 + t;
        int r = s >> 2;
        int g = (s & 3) ^ ((r >> 1) & 3);
        size_t offa = (size_t)(row0 + r) * 256 + g * 8;
        size_t offb = (size_t)r * 256 + g * 8;
        ld16(zh + offa, &Ah[0][s * 8]);
        ld16(zl + offa, &Al[0][s * 8]);
        ld16(wh + offb, &Bh[0][s * 8]);
        ld16(wl + offb, &Bl[0][s * 8]);
    }

    float bd[16];
    int   bi[16];
    #pragma unroll
    for (int s = 0; s < 16; s++) { bd[s] = FLT_MAX; bi[s] = 0; }

    f32x4 acc[4][4];

    // steps: tt = cc*8 + kc ; cc = tt>>3 (chunk of 128 codes), kc = tt&7
    #pragma unroll 2
    for (int tt = 0; tt < 128; ++tt) {
        const int kc  = tt & 7;
        const int cur = tt & 1;

        // stage step tt+1 into the other buffer, then wait only for step tt's
        // 8 loads (issued one full compute-phase ago) -> latency hidden.
        if (tt < 127) {
            const int t1 = tt + 1;
            const int cc1 = t1 >> 3, kc1 = t1 & 7, nb = t1 & 1;
            #pragma unroll
            for (int it = 0; it < 2; it++) {
                int s = it * 256 + t;
                int r = s >> 2;
                int g = (s & 3) ^ ((r >> 1) & 3);
                size_t offa = (size_t)(row0 + r) * 256 + kc1 * 32 + g * 8;
                size_t offb = (size_t)(cc1 * 128 + r) * 256 + kc1 * 32 + g * 8;
                ld16(zh + offa, &Ah[nb][s * 8]);
                ld16(zl + offa, &Al[nb][s * 8]);
                ld16(wh + offb, &Bh[nb][s * 8]);
                ld16(wl + offb, &Bl[nb][s * 8]);
            }
            asm volatile("s_waitcnt vmcnt(8)" ::: "memory");
        } else {
            asm volatile("s_waitcnt vmcnt(0)" ::: "memory");
        }
        __builtin_amdgcn_s_barrier();
        asm volatile("" ::: "memory");
        __builtin_amdgcn_sched_barrier(0);   // do not hoist ds_reads above barrier

        if (kc == 0) {
            #pragma unroll
            for (int i = 0; i < 4; i++)
                #pragma unroll
                for (int j = 0; j < 4; j++) acc[i][j] = (f32x4){0.f, 0.f, 0.f, 0.f};
        }

        const _Float16* Ahc = &Ah[cur][0];
        const _Float16* Alc = &Al[cur][0];
        const _Float16* Bhc = &Bh[cur][0];
        const _Float16* Blc = &Bl[cur][0];

        f16x8 ah[4], al[4];
        #pragma unroll
        for (int i = 0; i < 4; i++) {
            int off = (wr0 + i * 16 + l15) * 32 + p8;
            ah[i] = *(const f16x8*)&Ahc[off];
            al[i] = *(const f16x8*)&Alc[off];
        }
        __builtin_amdgcn_s_setprio(1);
        #pragma unroll
        for (int j = 0; j < 4; j++) {
            int offb = (wc0 + j * 16 + l15) * 32 + p8;
            f16x8 bh = *(const f16x8*)&Bhc[offb];
            f16x8 bl = *(const f16x8*)&Blc[offb];
            #pragma unroll
            for (int i = 0; i < 4; i++) {
                acc[i][j] = __builtin_amdgcn_mfma_f32_16x16x32_f16(ah[i], bh, acc[i][j], 0, 0, 0);
                acc[i][j] = __builtin_amdgcn_mfma_f32_16x16x32_f16(ah[i], bl, acc[i][j], 0, 0, 0);
                acc[i][j] = __builtin_amdgcn_mfma_f32_16x16x32_f16(al[i], bh, acc[i][j], 0, 0, 0);
            }
        }
        __builtin_amdgcn_s_setprio(0);

        // epilogue each 8th step: d = cbsq[c] - 2*dot ; codes ascend -> first-min kept
        if (kc == 7) {
            const int cc = tt >> 3;
            #pragma unroll
            for (int j = 0; j < 4; j++) {
                int c = cc * 128 + wc0 + j * 16 + l15;
                float csq = cbsq_lds[c];
                #pragma unroll
                for (int i = 0; i < 4; i++) {
                    #pragma unroll
                    for (int r = 0; r < 4; r++) {
                        float d = fmaf(-2.0f, acc[i][j][r], csq);
                        int s = i * 4 + r;
                        if (d < bd[s]) { bd[s] = d; bi[s] = c; }
                    }
                }
            }
        }
        asm volatile("" ::: "memory");
        __builtin_amdgcn_s_barrier();
    }

    // reduce across the 16 lanes (l15) holding the same rows; tie -> smaller index
    #pragma unroll
    for (int m = 1; m <= 8; m <<= 1) {
        #pragma unroll
        for (int s = 0; s < 16; s++) {
            float od = __shfl_xor(bd[s], m, 64);
            int   oi = __shfl_xor(bi[s], m, 64);
            if (od < bd[s] || (od == bd[s] && oi < bi[s])) { bd[s] = od; bi[s] = oi; }
        }
    }
    // overlay reduction arrays on A buffers (all staging complete after the loop)
    float* rD = (float*)&Ah[0][0];   // [2][128]
    int*   rI = (int*)&Al[0][0];     // [2][128]
    if (l15 == 0) {
        const int wc = wave & 1;
        #pragma unroll
        for (int i = 0; i < 4; i++) {
            #pragma unroll
            for (int r = 0; r < 4; r++) {
                int row = wr0 + i * 16 + quad * 4 + r;
                rD[wc * 128 + row] = bd[i * 4 + r];
                rI[wc * 128 + row] = bi[i * 4 + r];
            }
        }
    }
    __syncthreads();
    if (t < 128) {
        float d0 = rD[t];       int i0 = rI[t];
        float d1 = rD[128 + t]; int i1 = rI[128 + t];
        int best = (d1 < d0 || (d1 == d0 && i1 < i0)) ? i1 : i0;
        idx_out[row0 + t] = (float)best;
    }
}

// -------- gather + STE + commitment partial + histogram: one wave per row --------
__global__ void gather_kernel(const float* __restrict__ z, const float* __restrict__ cb,
                              const float* __restrict__ idx_f, float* __restrict__ out,
                              int* __restrict__ usage, float* __restrict__ accum) {
    int lane = threadIdx.x & 63;
    int wid  = (blockIdx.x * blockDim.x + threadIdx.x) >> 6;
    const float4* z4  = (const float4*)z;
    const float4* cb4 = (const float4*)cb;
    float4* o4 = (float4*)out;

    float local = 0.0f;
    for (int r = wid; r < NROWS; r += 4096) {
        int idx = (int)idx_f[r];
        float4 zv = z4[(size_t)r * 64 + lane];
        float4 w  = cb4[(size_t)idx * 64 + lane];
        float4 d, o;
        d.x = w.x - zv.x; d.y = w.y - zv.y; d.z = w.z - zv.z; d.w = w.w - zv.w;
        o.x = zv.x + d.x; o.y = zv.y + d.y; o.z = zv.z + d.z; o.w = zv.w + d.w;
        o4[(size_t)r * 64 + lane] = o;
        local = fmaf(d.x, d.x, local);
        local = fmaf(d.y, d.y, local);
        local = fmaf(d.z, d.z, local);
        local = fmaf(d.w, d.w, local);
        if (lane == 0) atomicAdd(&usage[idx], 1);
    }
    #pragma unroll
    for (int m = 32; m >= 1; m >>= 1) local += __shfl_xor(local, m, 64);
    if (lane == 0) atomicAdd(accum, local);
}

// -------- scalars: commitment mean + entropy loss --------
__global__ void finalize_kernel(const int* __restrict__ usage, const float* __restrict__ accum,
                                float* __restrict__ out2) {
    __shared__ float red[256];
    int t = threadIdx.x;
    float e = 0.0f;
    for (int b = t; b < NCODES; b += 256) {
        float p = (float)usage[b] * (1.0f / 65536.0f);
        e -= p * logf(p + 1e-10f);
    }
    red[t] = e;
    __syncthreads();
    if (t == 0) {
        float s = 0.0f;
        for (int k = 0; k < 256; k++) s += red[k];
        out2[0] = accum[0] / 16777216.0f;
        out2[1] = logf(2048.0f) - s;
    }
}

extern "C" void kernel_launch(void* const* d_in, const int* in_sizes, int n_in,
                              void* d_out, int out_size, void* d_ws, size_t ws_size,
                              hipStream_t stream) {
    const float* z  = (const float*)d_in[0];
    const float* cb = (const float*)d_in[1];

    float* out   = (float*)d_out;
    float* idx_f = out + (size_t)NROWS * DIM;   // float offset 16777216 (byte 67108864)
    float* out2  = idx_f + NROWS;

    // z hi/lo scratch lives in the zq output region (exactly 64 MB), overwritten
    // later by gather_kernel. 0..33554432: zh ; 33554432..67108864: zl.
    _Float16* zh = (_Float16*)d_out;
    _Float16* zl = zh + (size_t)NROWS * DIM;

    // ws: wh 1MB | wl 1MB | cbsq 8KB | usage 8KB | accum 4B
    _Float16* wh   = (_Float16*)d_ws;
    _Float16* wl   = wh + (size_t)NCODES * DIM;
    float*    cbsq = (float*)((char*)d_ws + 2097152);
    int*      usage= (int*)((char*)d_ws + 2105344);
    float*    accum= (float*)((char*)d_ws + 2113536);

    hipMemsetAsync((char*)d_ws + 2105344, 0, 8196, stream);
    split_all_kernel<<<8448, 256, 0, stream>>>(z, zh, zl, cb, wh, wl);
    cbsq_kernel<<<512, 256, 0, stream>>>(cb, cbsq);
    argmin_kernel<<<512, 256, 0, stream>>>(zh, zl, wh, wl, cbsq, idx_f);
    gather_kernel<<<1024, 256, 0, stream>>>(z, cb, idx_f, out, usage, accum);
    finalize_kernel<<<1, 256, 0, stream>>>(usage, accum, out2);
}

// Round 7
// 352.271 us; speedup vs baseline: 1.1834x; 1.1834x over previous
//
#include <hip/hip_runtime.h>
#include <float.h>
#include <math.h>

#define NROWS 65536
#define DIM 256
#define NCODES 2048

typedef _Float16 f16x8 __attribute__((ext_vector_type(8)));
typedef float    f32x4 __attribute__((ext_vector_type(4)));

__device__ __forceinline__ void ld16(const void* g, void* l) {
    __builtin_amdgcn_global_load_lds(
        (__attribute__((address_space(1))) void*)g,
        (__attribute__((address_space(3))) void*)l, 16, 0, 0);
}

// -------- split fp32 -> interleaved per-row (hi|lo) fp16, 8 elems/thread --------
// pk layout: row stride 512 halves = [h0..h255 | l0..l255]  (1 KB per row).
// This makes out-row r (1 KB fp32) overlap exactly row r's own h/l scratch,
// so the fused gather in argmin can overwrite it safely after its last A-read.
__global__ void split_all_kernel(const float* __restrict__ z, _Float16* __restrict__ zpk,
                                 const float* __restrict__ cb, _Float16* __restrict__ wpk) {
    int gid = blockIdx.x * 256 + threadIdx.x;
    const float* x; _Float16* pk; int i;
    if (blockIdx.x < 8192) { x = z;  pk = zpk; i = gid * 8; }
    else                   { x = cb; pk = wpk; i = (gid - 2097152) * 8; }
    int row = i >> 8, d = i & 255;
    float4 a = *(const float4*)(x + i);
    float4 b = *(const float4*)(x + i + 4);
    float v[8] = {a.x, a.y, a.z, a.w, b.x, b.y, b.z, b.w};
    _Float16 h[8], l[8];
    #pragma unroll
    for (int k = 0; k < 8; k++) {
        h[k] = (_Float16)v[k];
        l[k] = (_Float16)(v[k] - (float)h[k]);   // v - (float)h is exact in fp32
    }
    *(f16x8*)(pk + (size_t)row * 512 + d)       = *(const f16x8*)h;
    *(f16x8*)(pk + (size_t)row * 512 + 256 + d) = *(const f16x8*)l;
}

// -------- codebook squared norms (fp32 exact): one wave per code --------
// Kept bit-identical (summation order) to the verified version: cbsq bits
// feed the argmin decision; reordering risks flipping near-tie indices.
__global__ void cbsq_kernel(const float* __restrict__ cb, float* __restrict__ cbsq) {
    int wid  = (blockIdx.x * blockDim.x + threadIdx.x) >> 6;
    int lane = threadIdx.x & 63;
    const float4* c4 = (const float4*)cb;
    float4 v = c4[wid * 64 + lane];
    float s = v.x * v.x + v.y * v.y + v.z * v.z + v.w * v.w;
    #pragma unroll
    for (int m = 32; m >= 1; m >>= 1) s += __shfl_xor(s, m, 64);
    if (lane == 0) cbsq[wid] = s;
}

// -------- MFMA argmin + fused gather: 256 blocks x 512 thr (8 waves, 4x2) --------
// Main loop identical to the verified 198.7us kernel (same LDS layout, swizzle,
// vmcnt(8) double-buffer, MFMA order) -- only the GLOBAL staging offsets change
// (interleaved h|l row layout). After the index merge, the block gathers
// cb[idx], writes zq (STE), and accumulates commitment/usage for its own rows.
// dot = zh*wh + zh*wl + zl*wh  (fp16 split; zl*wl term ~2^-24, dropped)
__global__ __launch_bounds__(512, 2)
void argmin_kernel(const _Float16* __restrict__ zpk, const _Float16* __restrict__ wpk,
                   const float* __restrict__ cbsq, float* __restrict__ idx_out,
                   const float* __restrict__ z, const float* __restrict__ cb,
                   float* __restrict__ out, int* __restrict__ usage,
                   float* __restrict__ accum) {
    __shared__ _Float16 Ah[2][256 * 32];   // 2 x 16 KB
    __shared__ _Float16 Al[2][256 * 32];   // 2 x 16 KB
    __shared__ _Float16 Bh[2][256 * 32];   // 2 x 16 KB
    __shared__ _Float16 Bl[2][256 * 32];   // 2 x 16 KB
    __shared__ float cbsq_lds[NCODES];     // 8 KB (keeps vmcnt clean in epilogue)

    const int t    = threadIdx.x;
    const int wave = t >> 6;
    const int lane = t & 63;
    const int quad = lane >> 4;
    const int l15  = lane & 15;
    const int wr0  = (wave >> 1) * 64;    // wave row offset within block tile
    const int wc0  = (wave & 1) * 128;    // wave code offset within chunk
    const int row0 = blockIdx.x * 256;

    // swizzled read offset (granule of 8 halves): pos = quad ^ ((row>>1)&3)
    const int p8 = (quad ^ ((l15 >> 1) & 3)) * 8;

    // stage cbsq into LDS: 512 thr x 16 B = 8 KB
    ld16(cbsq + t * 4, &cbsq_lds[t * 4]);

    // prologue: stage step 0 (cc=0, kc=0) into buffer 0 (8 ld16/thread)
    #pragma unroll
    for (int it = 0; it < 2; it++) {
        int s = it * 512 + t;
        int r = s >> 2;
        int g = (s & 3) ^ ((r >> 1) & 3);
        size_t offa = (size_t)(row0 + r) * 512 + g * 8;
        size_t offb = (size_t)r * 512 + g * 8;
        ld16(zpk + offa,       &Ah[0][s * 8]);
        ld16(zpk + offa + 256, &Al[0][s * 8]);
        ld16(wpk + offb,       &Bh[0][s * 8]);
        ld16(wpk + offb + 256, &Bl[0][s * 8]);
    }

    float bd[16];
    int   bi[16];
    #pragma unroll
    for (int s = 0; s < 16; s++) { bd[s] = FLT_MAX; bi[s] = 0; }

    f32x4 acc[4][8];

    #pragma unroll 2
    for (int tt = 0; tt < 64; ++tt) {
        const int kc  = tt & 7;
        const int cur = tt & 1;

        // stage step tt+1 into the other buffer, then wait only for step tt's
        // 8 loads (issued one full compute-phase ago) -> latency hidden.
        if (tt < 63) {
            const int t1 = tt + 1;
            const int cc1 = t1 >> 3, kc1 = t1 & 7, nb = t1 & 1;
            #pragma unroll
            for (int it = 0; it < 2; it++) {
                int s = it * 512 + t;
                int r = s >> 2;
                int g = (s & 3) ^ ((r >> 1) & 3);
                size_t offa = (size_t)(row0 + r) * 512 + kc1 * 32 + g * 8;
                size_t offb = (size_t)(cc1 * 256 + r) * 512 + kc1 * 32 + g * 8;
                ld16(zpk + offa,       &Ah[nb][s * 8]);
                ld16(zpk + offa + 256, &Al[nb][s * 8]);
                ld16(wpk + offb,       &Bh[nb][s * 8]);
                ld16(wpk + offb + 256, &Bl[nb][s * 8]);
            }
            asm volatile("s_waitcnt vmcnt(8)" ::: "memory");
        } else {
            asm volatile("s_waitcnt vmcnt(0)" ::: "memory");
        }
        __builtin_amdgcn_s_barrier();
        asm volatile("" ::: "memory");
        __builtin_amdgcn_sched_barrier(0);   // do not hoist ds_reads above barrier

        if (kc == 0) {
            #pragma unroll
            for (int i = 0; i < 4; i++)
                #pragma unroll
                for (int j = 0; j < 8; j++) acc[i][j] = (f32x4){0.f, 0.f, 0.f, 0.f};
        }

        const _Float16* Ahc = &Ah[cur][0];
        const _Float16* Alc = &Al[cur][0];
        const _Float16* Bhc = &Bh[cur][0];
        const _Float16* Blc = &Bl[cur][0];

        f16x8 ah[4], al[4];
        #pragma unroll
        for (int i = 0; i < 4; i++) {
            int off = (wr0 + i * 16 + l15) * 32 + p8;
            ah[i] = *(const f16x8*)&Ahc[off];
            al[i] = *(const f16x8*)&Alc[off];
        }
        __builtin_amdgcn_s_setprio(1);
        #pragma unroll
        for (int j = 0; j < 8; j++) {
            int offb = (wc0 + j * 16 + l15) * 32 + p8;
            f16x8 bh = *(const f16x8*)&Bhc[offb];
            f16x8 bl = *(const f16x8*)&Blc[offb];
            #pragma unroll
            for (int i = 0; i < 4; i++) {
                acc[i][j] = __builtin_amdgcn_mfma_f32_16x16x32_f16(ah[i], bh, acc[i][j], 0, 0, 0);
                acc[i][j] = __builtin_amdgcn_mfma_f32_16x16x32_f16(ah[i], bl, acc[i][j], 0, 0, 0);
                acc[i][j] = __builtin_amdgcn_mfma_f32_16x16x32_f16(al[i], bh, acc[i][j], 0, 0, 0);
            }
        }
        __builtin_amdgcn_s_setprio(0);

        // epilogue each 8th step: d = cbsq[c] - 2*dot ; codes ascend -> first-min kept
        if (kc == 7) {
            const int cc = tt >> 3;
            #pragma unroll
            for (int j = 0; j < 8; j++) {
                int c = cc * 256 + wc0 + j * 16 + l15;
                float csq = cbsq_lds[c];
                #pragma unroll
                for (int i = 0; i < 4; i++) {
                    #pragma unroll
                    for (int r = 0; r < 4; r++) {
                        float d = fmaf(-2.0f, acc[i][j][r], csq);
                        int s = i * 4 + r;
                        if (d < bd[s]) { bd[s] = d; bi[s] = c; }
                    }
                }
            }
        }
        asm volatile("" ::: "memory");
        __builtin_amdgcn_s_barrier();
    }

    // reduce across the 16 lanes (l15) holding the same rows; tie -> smaller index
    #pragma unroll
    for (int m = 1; m <= 8; m <<= 1) {
        #pragma unroll
        for (int s = 0; s < 16; s++) {
            float od = __shfl_xor(bd[s], m, 64);
            int   oi = __shfl_xor(bi[s], m, 64);
            if (od < bd[s] || (od == bd[s] && oi < bi[s])) { bd[s] = od; bi[s] = oi; }
        }
    }
    // overlay reduction arrays on A buffers (all staging complete after the loop)
    float* rD = (float*)&Ah[0][0];   // [2][256]
    int*   rI = (int*)&Al[0][0];     // [2][256]
    int*   sI = (int*)&Bh[0][0];     // [256] final per-row index
    if (l15 == 0) {
        const int wc = wave & 1;
        #pragma unroll
        for (int i = 0; i < 4; i++) {
            #pragma unroll
            for (int r = 0; r < 4; r++) {
                int row = wr0 + i * 16 + quad * 4 + r;
                rD[wc * 256 + row] = bd[i * 4 + r];
                rI[wc * 256 + row] = bi[i * 4 + r];
            }
        }
    }
    __syncthreads();
    if (t < 256) {
        float d0 = rD[t];       int i0 = rI[t];
        float d1 = rD[256 + t]; int i1 = rI[256 + t];
        int best = (d1 < d0 || (d1 == d0 && i1 < i0)) ? i1 : i0;
        sI[t] = best;
        idx_out[row0 + t] = (float)best;
    }
    __syncthreads();

    // -------- fused gather + STE + commitment partial + histogram --------
    // All zpk reads for this block are complete (vmcnt(0) + barriers above),
    // and out rows [row0,row0+256) overlap only this block's own zpk rows.
    {
        const float4* z4  = (const float4*)z;
        const float4* cb4 = (const float4*)cb;
        float4* o4 = (float4*)out;
        float local = 0.0f;
        for (int rr = wave; rr < 256; rr += 8) {
            int idx = sI[rr];
            size_t grow = (size_t)(row0 + rr);
            float4 zv = z4[grow * 64 + lane];
            float4 w  = cb4[(size_t)idx * 64 + lane];
            float4 d, o;
            d.x = w.x - zv.x; d.y = w.y - zv.y; d.z = w.z - zv.z; d.w = w.w - zv.w;
            o.x = zv.x + d.x; o.y = zv.y + d.y; o.z = zv.z + d.z; o.w = zv.w + d.w;
            o4[grow * 64 + lane] = o;
            local = fmaf(d.x, d.x, local);
            local = fmaf(d.y, d.y, local);
            local = fmaf(d.z, d.z, local);
            local = fmaf(d.w, d.w, local);
            if (lane == 0) atomicAdd(&usage[idx], 1);
        }
        #pragma unroll
        for (int m = 32; m >= 1; m >>= 1) local += __shfl_xor(local, m, 64);
        if (lane == 0) atomicAdd(accum, local);
    }
}

// -------- scalars: commitment mean + entropy loss --------
__global__ void finalize_kernel(const int* __restrict__ usage, const float* __restrict__ accum,
                                float* __restrict__ out2) {
    __shared__ float red[256];
    int t = threadIdx.x;
    float e = 0.0f;
    for (int b = t; b < NCODES; b += 256) {
        float p = (float)usage[b] * (1.0f / 65536.0f);
        e -= p * logf(p + 1e-10f);
    }
    red[t] = e;
    __syncthreads();
    if (t == 0) {
        float s = 0.0f;
        for (int k = 0; k < 256; k++) s += red[k];
        out2[0] = accum[0] / 16777216.0f;
        out2[1] = logf(2048.0f) - s;
    }
}

extern "C" void kernel_launch(void* const* d_in, const int* in_sizes, int n_in,
                              void* d_out, int out_size, void* d_ws, size_t ws_size,
                              hipStream_t stream) {
    const float* z  = (const float*)d_in[0];
    const float* cb = (const float*)d_in[1];

    float* out   = (float*)d_out;
    float* idx_f = out + (size_t)NROWS * DIM;   // float offset 16777216 (byte 67108864)
    float* out2  = idx_f + NROWS;

    // z hi/lo scratch lives in the zq output region (exactly 64 MiB) with an
    // INTERLEAVED per-row layout [h(256)|l(256)] so the fused gather's out-row
    // write clobbers only the owning block's own rows.
    _Float16* zpk = (_Float16*)d_out;

    // ws: wpk 2MB (interleaved) | cbsq 8KB | usage 8KB | accum 4B
    _Float16* wpk  = (_Float16*)d_ws;
    float*    cbsq = (float*)((char*)d_ws + 2097152);
    int*      usage= (int*)((char*)d_ws + 2105344);
    float*    accum= (float*)((char*)d_ws + 2113536);

    hipMemsetAsync((char*)d_ws + 2105344, 0, 8196, stream);
    split_all_kernel<<<8448, 256, 0, stream>>>(z, zpk, cb, wpk);
    cbsq_kernel<<<512, 256, 0, stream>>>(cb, cbsq);
    argmin_kernel<<<256, 512, 0, stream>>>(zpk, wpk, cbsq, idx_f, z, cb, out, usage, accum);
    finalize_kernel<<<1, 256, 0, stream>>>(usage, accum, out2);
}